// Round 9
// baseline (176.248 us; speedup 1.0000x reference)
//
#include <hip/hip_runtime.h>
#include <cstddef>
#include <cstdint>

#define EPSBN 1e-5f
constexpr int B_ = 4, N_ = 2048, K_ = 20;

typedef __attribute__((ext_vector_type(8))) _Float16 half8v;
typedef __attribute__((ext_vector_type(4))) float f32x4;
typedef const __attribute__((address_space(1))) unsigned int* gas_t;
typedef __attribute__((address_space(3))) unsigned int* las_t;

// batch-XCD swizzle: block B -> (batch, local) with B&7 = XCD slot, batch b on slots {2b,2b+1}
__device__ __forceinline__ void swz_batch(int B, int& b, int& local) {
    b = (B & 7) >> 1;
    local = ((B >> 3) << 1) | (B & 1);
}

// order-preserving float<->uint key (memset-0 == -infinity under the mapping)
__device__ __forceinline__ unsigned fkey(float x) {
    unsigned u = __float_as_uint(x);
    return (u & 0x80000000u) ? ~u : (u | 0x80000000u);
}
__device__ __forceinline__ float funkey(unsigned k) {
    unsigned u = (k & 0x80000000u) ? (k ^ 0x80000000u) : ~k;
    return __uint_as_float(u);
}

// ---------------- fused weight prep (layers 1-3 conv + w4 cast) ----------------

__device__ __forceinline__ void prep_conv(const float* __restrict__ W, _Float16* __restrict__ W2h,
                                          int O, int C, int i) {
    int o = i / C, c = i - o * C;
    float a = W[o * 2 * C + c];
    float d = W[o * 2 * C + C + c] - a;
    W2h[(size_t)o * C + c] = (_Float16)a;
    W2h[(size_t)(O + o) * C + c] = (_Float16)d;
}

__global__ void k_prep_all(const float* __restrict__ w1, const float* __restrict__ w2,
                           const float* __restrict__ w3, const float* __restrict__ w4,
                           _Float16* __restrict__ W2h1, _Float16* __restrict__ W2h2,
                           _Float16* __restrict__ W2h3, _Float16* __restrict__ w4h) {
    int i = blockIdx.x * 256 + threadIdx.x;
    if (i < 8192) { prep_conv(w1, W2h1, 128, 64, i); return; }
    i -= 8192;
    if (i < 32768) { prep_conv(w2, W2h2, 256, 128, i); return; }
    i -= 32768;
    if (i < 131072) { prep_conv(w3, W2h3, 512, 256, i); return; }
    i -= 131072;
    if (i < 983040) w4h[i] = (_Float16)w4[i];
}

// ---------------- generic MFMA GEMM: out(fp16) = A (8192 x K, stride sa) @ Bw^T ----------------
// BM x 128 tile; 4 waves x ((BM/2) x 64); global_load_lds staging, XOR-swizzled LDS,
// single-buffer (r4/r5/r7: pipelining & in-GEMM transforms all neutral-to-negative).
template<bool STATS, int BM>
__global__ __launch_bounds__(256, 3)
void k_gemm(const _Float16* __restrict__ A, int sa,
            const _Float16* __restrict__ Bw, int K,
            _Float16* __restrict__ outp, int so,
            float* __restrict__ psum, float* __restrict__ psq) {
    constexpr int MI = BM / 32;
    __shared__ __align__(16) _Float16 Als[BM * 64];
    __shared__ __align__(16) _Float16 Bls[128 * 64];
    const int tid = threadIdx.x, lane = tid & 63, w = tid >> 6;
    int bsw, lsw;
    swz_batch(blockIdx.x, bsw, lsw);
    constexpr int TPB = 2048 / BM;
    const int m0 = (bsw * TPB + lsw) * BM;
    const int n0 = blockIdx.y * 128;
    const int wr = (w >> 1) * (BM / 2), wc = (w & 1) * 64;

    f32x4 acc[MI][4];
#pragma unroll
    for (int i = 0; i < MI; ++i)
#pragma unroll
        for (int j = 0; j < 4; ++j) acc[i][j] = (f32x4){0.f, 0.f, 0.f, 0.f};

    int srb[4], scb[4];
#pragma unroll
    for (int j = 0; j < 4; ++j) {
        int idx = w * 256 + j * 64 + lane;
        srb[j] = idx >> 3;
        scb[j] = ((idx & 7) ^ (srb[j] & 7)) * 8;
    }
    int sra[MI], sca[MI];
#pragma unroll
    for (int j = 0; j < MI; ++j) {
        int idx = w * (MI * 64) + j * 64 + lane;
        sra[j] = idx >> 3;
        sca[j] = ((idx & 7) ^ (sra[j] & 7)) * 8;
    }
    int aoff[MI][2], boff[4][2];
#pragma unroll
    for (int i = 0; i < MI; ++i) {
        int ra = wr + i * 16 + (lane & 15);
#pragma unroll
        for (int t = 0; t < 2; ++t)
            aoff[i][t] = ra * 64 + ((((lane >> 4) + t * 4) ^ (ra & 7)) * 8);
    }
#pragma unroll
    for (int j = 0; j < 4; ++j) {
        int rb = wc + j * 16 + (lane & 15);
#pragma unroll
        for (int t = 0; t < 2; ++t)
            boff[j][t] = rb * 64 + ((((lane >> 4) + t * 4) ^ (rb & 7)) * 8);
    }

    for (int c0 = 0; c0 < K; c0 += 64) {
#pragma unroll
        for (int j = 0; j < MI; ++j) {
            const _Float16* ga = &A[(size_t)(m0 + sra[j]) * sa + c0 + sca[j]];
            __builtin_amdgcn_global_load_lds((gas_t)(const void*)ga,
                                             (las_t)(void*)&Als[(w * MI * 64 + j * 64) * 8], 16, 0, 0);
        }
#pragma unroll
        for (int j = 0; j < 4; ++j) {
            const _Float16* gb = &Bw[(size_t)(n0 + srb[j]) * K + c0 + scb[j]];
            __builtin_amdgcn_global_load_lds((gas_t)(const void*)gb,
                                             (las_t)(void*)&Bls[(w * 256 + j * 64) * 8], 16, 0, 0);
        }
        __syncthreads();
#pragma unroll
        for (int t = 0; t < 2; ++t) {
            half8v a[MI], b[4];
#pragma unroll
            for (int i = 0; i < MI; ++i) a[i] = *(const half8v*)&Als[aoff[i][t]];
#pragma unroll
            for (int j = 0; j < 4; ++j) b[j] = *(const half8v*)&Bls[boff[j][t]];
#pragma unroll
            for (int i = 0; i < MI; ++i)
#pragma unroll
                for (int j = 0; j < 4; ++j)
                    acc[i][j] = __builtin_amdgcn_mfma_f32_16x16x32_f16(a[i], b[j], acc[i][j], 0, 0, 0);
        }
        __syncthreads();
    }
#pragma unroll
    for (int i = 0; i < MI; ++i)
#pragma unroll
        for (int j = 0; j < 4; ++j)
#pragma unroll
            for (int e = 0; e < 4; ++e) {
                int row = m0 + wr + i * 16 + (lane >> 4) * 4 + e;
                int col = n0 + wc + j * 16 + (lane & 15);
                outp[(size_t)row * so + col] = (_Float16)acc[i][j][e];
            }
    if constexpr (STATS) {
        int slice = blockIdx.x & 63;
#pragma unroll
        for (int j = 0; j < 4; ++j) {
            float s = 0.f, q = 0.f;
#pragma unroll
            for (int i = 0; i < MI; ++i)
#pragma unroll
                for (int e = 0; e < 4; ++e) {
                    float v = acc[i][j][e];
                    s += v; q += v * v;
                }
            s += __shfl_xor(s, 16); s += __shfl_xor(s, 32);
            q += __shfl_xor(q, 16); q += __shfl_xor(q, 32);
            if ((lane >> 4) == 0) {
                int col = n0 + wc + j * 16 + lane;
                atomicAdd(&psum[slice * 1024 + col], s);
                atomicAdd(&psq[slice * 1024 + col], q);
            }
        }
    }
}

// ---------------- layer-0: fused dense (C=3) + gather-reduce + BN stats ----------------
__global__ __launch_bounds__(256)
void k_gather0(const float* __restrict__ x, const float* __restrict__ w0,
               const int* __restrict__ nidx, const float* __restrict__ g,
               _Float16* __restrict__ exth,
               float* __restrict__ psum, float* __restrict__ psq) {
    constexpr int O = 64, VPT = 8, P = 32;
    __shared__ float s_red[P * O];
    __shared__ float q_red[P * O];
    const int tid = threadIdx.x;
    const int pl = tid / VPT, v = tid % VPT;
    int bsw, local;
    swz_batch(blockIdx.x, bsw, local);
    const int bbase = bsw * N_;
    const int p = bbase + local * P + pl;
    float wa[8][3], wd[8][3], sg[8];
#pragma unroll
    for (int e = 0; e < 8; ++e) {
        int o = v * 8 + e;
        float a0 = w0[o * 6], a1 = w0[o * 6 + 1], a2 = w0[o * 6 + 2];
        wa[e][0] = a0; wa[e][1] = a1; wa[e][2] = a2;
        wd[e][0] = w0[o * 6 + 3] - a0;
        wd[e][1] = w0[o * 6 + 4] - a1;
        wd[e][2] = w0[o * 6 + 5] - a2;
        sg[e] = (g[o] >= 0.f) ? 1.f : -1.f;
    }
    float mx[8], sm[8], sq[8];
#pragma unroll
    for (int e = 0; e < 8; ++e) { mx[e] = -3.4e38f; sm[e] = 0.f; sq[e] = 0.f; }
    const int* np = nidx + p * K_;
#pragma unroll 4
    for (int k = 0; k < K_; ++k) {
        int j = bbase + np[k];
        float x0 = x[j * 3], x1 = x[j * 3 + 1], x2 = x[j * 3 + 2];
#pragma unroll
        for (int e = 0; e < 8; ++e) {
            float f = wa[e][0] * x0 + wa[e][1] * x1 + wa[e][2] * x2;
            mx[e] = fmaxf(mx[e], f * sg[e]);
            sm[e] += f;
            sq[e] += f * f;
        }
    }
    float xp0 = x[p * 3], xp1 = x[p * 3 + 1], xp2 = x[p * 3 + 2];
    const float Kf = (float)K_;
    half8v exo;
#pragma unroll
    for (int e = 0; e < 8; ++e) {
        float zf = wd[e][0] * xp0 + wd[e][1] * xp1 + wd[e][2] * xp2;
        exo[e] = (_Float16)(sg[e] * mx[e] + zf);
        s_red[pl * O + v * 8 + e] = sm[e] + Kf * zf;
        q_red[pl * O + v * 8 + e] = sq[e] + 2.f * zf * sm[e] + Kf * zf * zf;
    }
    *(half8v*)&exth[(size_t)p * O + v * 8] = exo;
    __syncthreads();
    int slice = blockIdx.x & 63;
    for (int ch = tid; ch < O; ch += 256) {
        float s = 0.f, q = 0.f;
#pragma unroll
        for (int pp = 0; pp < P; ++pp) { s += s_red[pp * O + ch]; q += q_red[pp * O + ch]; }
        atomicAdd(&psum[slice * 1024 + ch], s);
        atomicAdd(&psq[slice * 1024 + ch], q);
    }
}

// ---------------- gather-reduce + fused BN stats (single extremum, batch-XCD-swizzled) ----------------
template<int O>
__global__ __launch_bounds__(256)
void k_gather(const _Float16* __restrict__ Z, const int* __restrict__ nidx,
              const float* __restrict__ g,
              _Float16* __restrict__ exth,
              float* __restrict__ psum, float* __restrict__ psq) {
    constexpr int VPT = O / 8, P = 256 / VPT;
    __shared__ float s_red[P * O];
    __shared__ float q_red[P * O];
    const int tid = threadIdx.x;
    const int pl = tid / VPT, v = tid % VPT;
    int bsw, local;
    swz_batch(blockIdx.x, bsw, local);
    const int bbase = bsw * N_;
    const int p = bbase + local * P + pl;
    float sg[8];
#pragma unroll
    for (int e = 0; e < 8; ++e) sg[e] = (g[v * 8 + e] >= 0.f) ? 1.f : -1.f;
    float mx[8], sm[8], sq[8];
#pragma unroll
    for (int e = 0; e < 8; ++e) { mx[e] = -3.4e38f; sm[e] = 0.f; sq[e] = 0.f; }
    const int* np = nidx + p * K_;
#pragma unroll 4
    for (int k = 0; k < K_; ++k) {
        int j = np[k];
        half8v z = *(const half8v*)&Z[(size_t)(bbase + j) * (2 * O) + v * 8];
#pragma unroll
        for (int e = 0; e < 8; ++e) {
            float f = (float)z[e];
            mx[e] = fmaxf(mx[e], f * sg[e]);
            sm[e] += f;
            sq[e] += f * f;
        }
    }
    half8v zd = *(const half8v*)&Z[(size_t)p * (2 * O) + O + v * 8];
    const float Kf = (float)K_;
    half8v exo;
#pragma unroll
    for (int e = 0; e < 8; ++e) {
        float zf = (float)zd[e];
        exo[e] = (_Float16)(sg[e] * mx[e] + zf);
        s_red[pl * O + v * 8 + e] = sm[e] + Kf * zf;
        q_red[pl * O + v * 8 + e] = sq[e] + 2.f * zf * sm[e] + Kf * zf * zf;
    }
    *(half8v*)&exth[(size_t)p * O + v * 8] = exo;
    __syncthreads();
    int slice = blockIdx.x & 63;
    for (int ch = tid; ch < O; ch += 256) {
        float s = 0.f, q = 0.f;
#pragma unroll
        for (int pp = 0; pp < P; ++pp) { s += s_red[pp * O + ch]; q += q_red[pp * O + ch]; }
        atomicAdd(&psum[slice * 1024 + ch], s);
        atomicAdd(&psq[slice * 1024 + ch], q);
    }
}

// ---------------- fused finalize + BN-apply (replaces k_finalize_sl + k_bn_apply) ----------------
// Each block: (128-point tile) x (64-channel tile).  Phase 1: reduce the 64 stat slices for
// ITS 64 channels only (~8K L2 loads -- cheap, unlike r7's per-N-tile full redundancy) into
// LDS scale/shift.  Phase 2: apply BN+lrelu to its 128x64 slab exth -> cath.
// Stats are device-scope atomics completed at producer kernel boundary -> visible, no fence.
template<int O>
__global__ __launch_bounds__(256)
void k_bnfin(const _Float16* __restrict__ exth,
             const float* __restrict__ psum, const float* __restrict__ psq,
             const float* __restrict__ g, const float* __restrict__ b, float cntInv,
             _Float16* __restrict__ cath, int coff) {
    constexpr int NCT = O / 64;                      // channel tiles
    __shared__ float part_s[64][4];
    __shared__ float part_q[64][4];
    __shared__ float scale_s[64], shift_s[64];
    const int tid = threadIdx.x;
    const int ct = blockIdx.x % NCT;
    const int ptile = blockIdx.x / NCT;              // [0,64)
    int bsw, local;
    swz_batch(ptile, bsw, local);                    // local in [0,16)
    const int ch0 = ct * 64;
    {   // phase 1: per-channel slice reduction (4 threads/channel, 16 slices each)
        int lc = tid >> 2, q = tid & 3;
        int ch = ch0 + lc;
        float s = 0.f, qq = 0.f;
        for (int i = q * 16; i < q * 16 + 16; ++i) {
            s += psum[i * 1024 + ch];
            qq += psq[i * 1024 + ch];
        }
        part_s[lc][q] = s; part_q[lc][q] = qq;
    }
    __syncthreads();
    if ((tid & 3) == 0) {
        int lc = tid >> 2;
        float s = part_s[lc][0] + part_s[lc][1] + part_s[lc][2] + part_s[lc][3];
        float qq = part_q[lc][0] + part_q[lc][1] + part_q[lc][2] + part_q[lc][3];
        float m = s * cntInv;
        float v = qq * cntInv - m * m;
        float sc = g[ch0 + lc] * rsqrtf(fmaxf(v, 0.f) + EPSBN);
        scale_s[lc] = sc;
        shift_s[lc] = b[ch0 + lc] - m * sc;
    }
    __syncthreads();
    // phase 2: apply to 128 points x 64 channels
    const int pbase = bsw * N_ + local * 128;
#pragma unroll
    for (int r = 0; r < 4; ++r) {
        int idx = r * 256 + tid;
        int ptl = idx >> 3;                          // [0,128)
        int cb = (idx & 7) * 8;                      // [0,64) in steps of 8
        int p = pbase + ptl;
        half8v hx = *(const half8v*)&exth[(size_t)p * O + ch0 + cb];
        half8v rr;
#pragma unroll
        for (int e = 0; e < 8; ++e) {
            float y = scale_s[cb + e] * (float)hx[e] + shift_s[cb + e];
            rr[e] = (_Float16)(y > 0.f ? y : 0.2f * y);
        }
        *(half8v*)&cath[(size_t)p * 960 + coff + ch0 + cb] = rr;
    }
}

// ---------------- finalize for the w4 layer only (feats_out consumes scale/shift) ----------------
__global__ void k_finalize_sl(const float* __restrict__ psum, const float* __restrict__ psq,
                              const float* __restrict__ g, const float* __restrict__ b,
                              float cntInv, int O,
                              float* __restrict__ scale, float* __restrict__ shift) {
    int o = blockIdx.x * 256 + threadIdx.x;
    if (o >= O) return;
    float s = 0.f, q = 0.f;
    for (int i = 0; i < 64; ++i) { s += psum[i * 1024 + o]; q += psq[i * 1024 + o]; }
    float m = s * cntInv;
    float v = q * cntInv - m * m;
    float sc = g[o] * rsqrtf(fmaxf(v, 0.f) + EPSBN);
    scale[o] = sc;
    shift[o] = b[o] - m * sc;
}

// BN+lrelu on Y4 (B,N,1024 fp16), transposed store -> fo (B,1024,N f32),
// pool fused via device atomics into z0: [b][0..1023]=ordered-uint max key, [1024..2047]=sum.
// z0 memset-0 upfront (key 0 == -inf under fkey mapping).
__global__ void k_feats_out(const _Float16* __restrict__ Y4, const float* __restrict__ scale,
                            const float* __restrict__ shift, float* __restrict__ fo,
                            float* __restrict__ z0) {
    __shared__ float tile[32][33];
    int tx = threadIdx.x, ty = threadIdx.y;      // (32,8)
    int b = blockIdx.z;
    int n0 = blockIdx.x * 32, c0 = blockIdx.y * 32;
#pragma unroll
    for (int i = 0; i < 4; ++i) {
        int n = n0 + ty + i * 8;
        int c = c0 + tx;
        float v = (float)Y4[((size_t)(b * N_ + n)) * 1024 + c];
        v = scale[c] * v + shift[c];
        v = v > 0.f ? v : 0.2f * v;
        tile[ty + i * 8][tx] = v;
    }
    __syncthreads();
#pragma unroll
    for (int i = 0; i < 4; ++i) {
        int c = c0 + ty + i * 8;
        int n = n0 + tx;
        float v2 = tile[tx][ty + i * 8];
        fo[((size_t)(b * 1024 + c)) * N_ + n] = v2;
        float mx = v2, s = v2;
#pragma unroll
        for (int d = 1; d < 32; d <<= 1) {
            mx = fmaxf(mx, __shfl_xor(mx, d));
            s += __shfl_xor(s, d);
        }
        if (tx == 0) {
            atomicMax((unsigned*)&z0[b * 2048 + c], fkey(mx));
            atomicAdd(&z0[b * 2048 + 1024 + c], s);
        }
    }
}

// ---------------- FC: one wave per (batch, output); optional fused batch-BN+lrelu ----------------
// pool!=0: zin row is [max-keys(1024) | raw-sums(1024)] -> unmap key / scale mean inline.
// c-iteration spans 256 consecutive elems; 1024 boundary is a multiple of 256 -> wave-uniform branch.
__global__ void k_fc(const float* __restrict__ zin, const float* __restrict__ W,
                     const float* __restrict__ bias,
                     const float* __restrict__ gg, const float* __restrict__ gb,
                     int C, int O, int pool, float* __restrict__ zout) {
    __shared__ float sh4[4];
    const int b = threadIdx.x >> 6;
    const int lane = threadIdx.x & 63;
    const int o = blockIdx.x;
    const float* wr = W + (size_t)o * C;
    const float* zr = zin + b * C;
    float s = 0.f;
    for (int c = lane * 4; c < C; c += 256) {
        const float4 wv = *(const float4*)&wr[c];
        float4 zv = *(const float4*)&zr[c];
        if (pool) {
            if (c < 1024) {
                zv.x = funkey(__float_as_uint(zv.x));
                zv.y = funkey(__float_as_uint(zv.y));
                zv.z = funkey(__float_as_uint(zv.z));
                zv.w = funkey(__float_as_uint(zv.w));
            } else {
                const float inv = 1.f / N_;
                zv.x *= inv; zv.y *= inv; zv.z *= inv; zv.w *= inv;
            }
        }
        s += wv.x * zv.x + wv.y * zv.y + wv.z * zv.z + wv.w * zv.w;
    }
    s += __shfl_xor(s, 1);
    s += __shfl_xor(s, 2);
    s += __shfl_xor(s, 4);
    s += __shfl_xor(s, 8);
    s += __shfl_xor(s, 16);
    s += __shfl_xor(s, 32);
    if (!gg) {
        if (lane == 0) zout[b * O + o] = s + (bias ? bias[o] : 0.f);
        return;
    }
    if (lane == 0) sh4[b] = s + (bias ? bias[o] : 0.f);
    __syncthreads();
    if (threadIdx.x == 0) {
        float v0 = sh4[0], v1 = sh4[1], v2 = sh4[2], v3 = sh4[3];
        float m = 0.25f * (v0 + v1 + v2 + v3);
        float d0 = v0 - m, d1 = v1 - m, d2 = v2 - m, d3 = v3 - m;
        float var = 0.25f * (d0 * d0 + d1 * d1 + d2 * d2 + d3 * d3);
        float sc = gg[o] * rsqrtf(var + EPSBN);
        float shv = gb[o];
        float r0 = sc * d0 + shv, r1 = sc * d1 + shv, r2 = sc * d2 + shv, r3 = sc * d3 + shv;
        zout[o]         = r0 > 0.f ? r0 : 0.2f * r0;
        zout[O + o]     = r1 > 0.f ? r1 : 0.2f * r1;
        zout[2 * O + o] = r2 > 0.f ? r2 : 0.2f * r2;
        zout[3 * O + o] = r3 > 0.f ? r3 : 0.2f * r3;
    }
}

// ---------------- launch ----------------

extern "C" void kernel_launch(void* const* d_in, const int* in_sizes, int n_in,
                              void* d_out, int out_size, void* d_ws, size_t ws_size,
                              hipStream_t stream) {
    const float* x    = (const float*)d_in[0];
    const int*   nidx = (const int*)d_in[1];
    const float* w[5]  = {(const float*)d_in[2], (const float*)d_in[5], (const float*)d_in[8],
                          (const float*)d_in[11], (const float*)d_in[14]};
    const float* g[5]  = {(const float*)d_in[3], (const float*)d_in[6], (const float*)d_in[9],
                          (const float*)d_in[12], (const float*)d_in[15]};
    const float* bb[5] = {(const float*)d_in[4], (const float*)d_in[7], (const float*)d_in[10],
                          (const float*)d_in[13], (const float*)d_in[16]};
    const float* lw1 = (const float*)d_in[17];
    const float* g6  = (const float*)d_in[18];
    const float* b6  = (const float*)d_in[19];
    const float* lw2 = (const float*)d_in[20];
    const float* lb2 = (const float*)d_in[21];
    const float* g7  = (const float*)d_in[22];
    const float* b7  = (const float*)d_in[23];
    const float* lw3 = (const float*)d_in[24];
    const float* lb3 = (const float*)d_in[25];

    float* out = (float*)d_out;
    float* fo  = out + 1024;              // feats (B,1024,N)

    uint8_t* base8 = (uint8_t*)d_ws;
    size_t off = 0;
    auto alloc = [&](size_t bytes) -> void* {
        void* r = base8 + off;
        off += (bytes + 255) & ~(size_t)255;
        return r;
    };
    _Float16* cath = (_Float16*)alloc((size_t)B_ * N_ * 960 * 2);   // 15.7 MB
    _Float16* Z    = (_Float16*)alloc((size_t)8192 * 1024 * 2);     // 16.8 MB
    _Float16* exth = (_Float16*)alloc((size_t)8192 * 512 * 2);      // 8.4 MB
    _Float16* Y4   = (_Float16*)alloc((size_t)8192 * 1024 * 2);     // 16.8 MB
    _Float16* W2h1 = (_Float16*)alloc((size_t)256 * 64 * 2);
    _Float16* W2h2 = (_Float16*)alloc((size_t)512 * 128 * 2);
    _Float16* W2h3 = (_Float16*)alloc((size_t)1024 * 256 * 2);
    _Float16* w4h  = (_Float16*)alloc((size_t)1024 * 960 * 2);
    float* psumall = (float*)alloc((size_t)5 * 131072 * 4);         // 2.6 MB, 5 regions
    float* z0      = (float*)alloc(8192 * 4);                       // contiguous after psumall
    float* scalev  = (float*)alloc(1024 * 4);
    float* shiftv  = (float*)alloc(1024 * 4);
    float* z1    = (float*)alloc(4096 * 4);
    float* z2    = (float*)alloc(2048 * 4);
    (void)ws_size; (void)in_sizes; (void)n_in; (void)out_size;

    auto psumR = [&](int r) { return psumall + (size_t)r * 131072; };
    auto psqR  = [&](int r) { return psumall + (size_t)r * 131072 + 65536; };

    // one upfront zero of all stat regions + z0 pool accumulators (contiguous), one prep launch
    hipMemsetAsync(psumall, 0, (size_t)5 * 131072 * 4 + 8192 * 4, stream);
    k_prep_all<<<(8192 + 32768 + 131072 + 983040 + 255) / 256, 256, 0, stream>>>(
        w[1], w[2], w[3], w[4], W2h1, W2h2, W2h3, w4h);

    const float invK = 1.f / (B_ * N_ * K_);

    // ---- layer 0 (C=3 -> O=64): fused dense + gather, then fused finalize+BN ----
    k_gather0<<<256, 256, 0, stream>>>(x, w[0], nidx, g[0], exth, psumR(0), psqR(0));
    k_bnfin<64><<<64, 256, 0, stream>>>(exth, psumR(0), psqR(0), g[0], bb[0], invK, cath, 0);

    // ---- layers 1-3: dense MFMA GEMM + fused gather + fused finalize+BN ----
    k_gemm<false, 64><<<dim3(128, 2), 256, 0, stream>>>(cath + 0, 960, W2h1, 64,
                                                        Z, 256, nullptr, nullptr);
    k_gather<128><<<512, 256, 0, stream>>>(Z, nidx, g[1], exth, psumR(1), psqR(1));
    k_bnfin<128><<<128, 256, 0, stream>>>(exth, psumR(1), psqR(1), g[1], bb[1], invK, cath, 64);

    k_gemm<false, 128><<<dim3(64, 4), 256, 0, stream>>>(cath + 64, 960, W2h2, 128,
                                                        Z, 512, nullptr, nullptr);
    k_gather<256><<<1024, 256, 0, stream>>>(Z, nidx, g[2], exth, psumR(2), psqR(2));
    k_bnfin<256><<<256, 256, 0, stream>>>(exth, psumR(2), psqR(2), g[2], bb[2], invK, cath, 192);

    k_gemm<false, 128><<<dim3(64, 8), 256, 0, stream>>>(cath + 192, 960, W2h3, 256,
                                                        Z, 1024, nullptr, nullptr);
    k_gather<512><<<2048, 256, 0, stream>>>(Z, nidx, g[3], exth, psumR(3), psqR(3));
    k_bnfin<512><<<512, 256, 0, stream>>>(exth, psumR(3), psqR(3), g[3], bb[3], invK, cath, 448);

    // ---- feats = lrelu(bn(w4 @ cat)) with fused column stats; pool fused via atomics ----
    k_gemm<true, 128><<<dim3(64, 8), 256, 0, stream>>>(cath, 960, w4h, 960, Y4, 1024,
                                                       psumR(4), psqR(4));
    k_finalize_sl<<<4, 256, 0, stream>>>(psumR(4), psqR(4), g[4], bb[4], 1.f / (B_ * N_), 1024,
                                         scalev, shiftv);
    k_feats_out<<<dim3(64, 32, 4), dim3(32, 8), 0, stream>>>(Y4, scalev, shiftv, fo, z0);

    // ---- FC head (BN fused into FC blocks; fc1 unmaps pooled keys/means inline) ----
    k_fc<<<1024, 256, 0, stream>>>(z0, lw1, nullptr, g6, b6, 2048, 1024, 1, z1);
    k_fc<<<512, 256, 0, stream>>>(z1, lw2, lb2, g7, b7, 1024, 512, 0, z2);
    k_fc<<<256, 256, 0, stream>>>(z2, lw3, lb3, nullptr, nullptr, 512, 256, 0, out);
}

// Round 10
// 162.923 us; speedup vs baseline: 1.0818x; 1.0818x over previous
//
#include <hip/hip_runtime.h>
#include <cstddef>
#include <cstdint>

#define EPSBN 1e-5f
constexpr int B_ = 4, N_ = 2048, K_ = 20;

typedef __attribute__((ext_vector_type(8))) _Float16 half8v;
typedef __attribute__((ext_vector_type(4))) float f32x4;
typedef const __attribute__((address_space(1))) unsigned int* gas_t;
typedef __attribute__((address_space(3))) unsigned int* las_t;

// batch-XCD swizzle: block B -> (batch, local) with B&7 = XCD slot, batch b on slots {2b,2b+1}
__device__ __forceinline__ void swz_batch(int B, int& b, int& local) {
    b = (B & 7) >> 1;
    local = ((B >> 3) << 1) | (B & 1);
}

// ---------------- fused weight prep (layers 1-3 conv + w4 cast) ----------------

__device__ __forceinline__ void prep_conv(const float* __restrict__ W, _Float16* __restrict__ W2h,
                                          int O, int C, int i) {
    int o = i / C, c = i - o * C;
    float a = W[o * 2 * C + c];
    float d = W[o * 2 * C + C + c] - a;
    W2h[(size_t)o * C + c] = (_Float16)a;
    W2h[(size_t)(O + o) * C + c] = (_Float16)d;
}

__global__ void k_prep_all(const float* __restrict__ w1, const float* __restrict__ w2,
                           const float* __restrict__ w3, const float* __restrict__ w4,
                           _Float16* __restrict__ W2h1, _Float16* __restrict__ W2h2,
                           _Float16* __restrict__ W2h3, _Float16* __restrict__ w4h) {
    int i = blockIdx.x * 256 + threadIdx.x;
    if (i < 8192) { prep_conv(w1, W2h1, 128, 64, i); return; }
    i -= 8192;
    if (i < 32768) { prep_conv(w2, W2h2, 256, 128, i); return; }
    i -= 32768;
    if (i < 131072) { prep_conv(w3, W2h3, 512, 256, i); return; }
    i -= 131072;
    if (i < 983040) w4h[i] = (_Float16)w4[i];
}

// ---------------- generic MFMA GEMM: out(fp16) = A (8192 x K, stride sa) @ Bw^T ----------------
// BM x 128 tile; 4 waves x ((BM/2) x 64); global_load_lds staging, XOR-swizzled LDS,
// single-buffer (r4/r5/r7: pipelining & in-GEMM transforms all neutral-to-negative).
template<bool STATS, int BM>
__global__ __launch_bounds__(256, 3)
void k_gemm(const _Float16* __restrict__ A, int sa,
            const _Float16* __restrict__ Bw, int K,
            _Float16* __restrict__ outp, int so,
            float* __restrict__ psum, float* __restrict__ psq) {
    constexpr int MI = BM / 32;
    __shared__ __align__(16) _Float16 Als[BM * 64];
    __shared__ __align__(16) _Float16 Bls[128 * 64];
    const int tid = threadIdx.x, lane = tid & 63, w = tid >> 6;
    int bsw, lsw;
    swz_batch(blockIdx.x, bsw, lsw);
    constexpr int TPB = 2048 / BM;
    const int m0 = (bsw * TPB + lsw) * BM;
    const int n0 = blockIdx.y * 128;
    const int wr = (w >> 1) * (BM / 2), wc = (w & 1) * 64;

    f32x4 acc[MI][4];
#pragma unroll
    for (int i = 0; i < MI; ++i)
#pragma unroll
        for (int j = 0; j < 4; ++j) acc[i][j] = (f32x4){0.f, 0.f, 0.f, 0.f};

    int srb[4], scb[4];
#pragma unroll
    for (int j = 0; j < 4; ++j) {
        int idx = w * 256 + j * 64 + lane;
        srb[j] = idx >> 3;
        scb[j] = ((idx & 7) ^ (srb[j] & 7)) * 8;
    }
    int sra[MI], sca[MI];
#pragma unroll
    for (int j = 0; j < MI; ++j) {
        int idx = w * (MI * 64) + j * 64 + lane;
        sra[j] = idx >> 3;
        sca[j] = ((idx & 7) ^ (sra[j] & 7)) * 8;
    }
    int aoff[MI][2], boff[4][2];
#pragma unroll
    for (int i = 0; i < MI; ++i) {
        int ra = wr + i * 16 + (lane & 15);
#pragma unroll
        for (int t = 0; t < 2; ++t)
            aoff[i][t] = ra * 64 + ((((lane >> 4) + t * 4) ^ (ra & 7)) * 8);
    }
#pragma unroll
    for (int j = 0; j < 4; ++j) {
        int rb = wc + j * 16 + (lane & 15);
#pragma unroll
        for (int t = 0; t < 2; ++t)
            boff[j][t] = rb * 64 + ((((lane >> 4) + t * 4) ^ (rb & 7)) * 8);
    }

    for (int c0 = 0; c0 < K; c0 += 64) {
#pragma unroll
        for (int j = 0; j < MI; ++j) {
            const _Float16* ga = &A[(size_t)(m0 + sra[j]) * sa + c0 + sca[j]];
            __builtin_amdgcn_global_load_lds((gas_t)(const void*)ga,
                                             (las_t)(void*)&Als[(w * MI * 64 + j * 64) * 8], 16, 0, 0);
        }
#pragma unroll
        for (int j = 0; j < 4; ++j) {
            const _Float16* gb = &Bw[(size_t)(n0 + srb[j]) * K + c0 + scb[j]];
            __builtin_amdgcn_global_load_lds((gas_t)(const void*)gb,
                                             (las_t)(void*)&Bls[(w * 256 + j * 64) * 8], 16, 0, 0);
        }
        __syncthreads();
#pragma unroll
        for (int t = 0; t < 2; ++t) {
            half8v a[MI], b[4];
#pragma unroll
            for (int i = 0; i < MI; ++i) a[i] = *(const half8v*)&Als[aoff[i][t]];
#pragma unroll
            for (int j = 0; j < 4; ++j) b[j] = *(const half8v*)&Bls[boff[j][t]];
#pragma unroll
            for (int i = 0; i < MI; ++i)
#pragma unroll
                for (int j = 0; j < 4; ++j)
                    acc[i][j] = __builtin_amdgcn_mfma_f32_16x16x32_f16(a[i], b[j], acc[i][j], 0, 0, 0);
        }
        __syncthreads();
    }
#pragma unroll
    for (int i = 0; i < MI; ++i)
#pragma unroll
        for (int j = 0; j < 4; ++j)
#pragma unroll
            for (int e = 0; e < 4; ++e) {
                int row = m0 + wr + i * 16 + (lane >> 4) * 4 + e;
                int col = n0 + wc + j * 16 + (lane & 15);
                outp[(size_t)row * so + col] = (_Float16)acc[i][j][e];
            }
    if constexpr (STATS) {
        int slice = blockIdx.x & 63;
#pragma unroll
        for (int j = 0; j < 4; ++j) {
            float s = 0.f, q = 0.f;
#pragma unroll
            for (int i = 0; i < MI; ++i)
#pragma unroll
                for (int e = 0; e < 4; ++e) {
                    float v = acc[i][j][e];
                    s += v; q += v * v;
                }
            s += __shfl_xor(s, 16); s += __shfl_xor(s, 32);
            q += __shfl_xor(q, 16); q += __shfl_xor(q, 32);
            if ((lane >> 4) == 0) {
                int col = n0 + wc + j * 16 + lane;
                atomicAdd(&psum[slice * 1024 + col], s);
                atomicAdd(&psq[slice * 1024 + col], q);
            }
        }
    }
}

// ---------------- layer-0: fused dense (C=3) + gather-reduce + BN stats ----------------
__global__ __launch_bounds__(256)
void k_gather0(const float* __restrict__ x, const float* __restrict__ w0,
               const int* __restrict__ nidx, const float* __restrict__ g,
               _Float16* __restrict__ exth,
               float* __restrict__ psum, float* __restrict__ psq) {
    constexpr int O = 64, VPT = 8, P = 32;
    __shared__ float s_red[P * O];
    __shared__ float q_red[P * O];
    const int tid = threadIdx.x;
    const int pl = tid / VPT, v = tid % VPT;
    int bsw, local;
    swz_batch(blockIdx.x, bsw, local);
    const int bbase = bsw * N_;
    const int p = bbase + local * P + pl;
    float wa[8][3], wd[8][3], sg[8];
#pragma unroll
    for (int e = 0; e < 8; ++e) {
        int o = v * 8 + e;
        float a0 = w0[o * 6], a1 = w0[o * 6 + 1], a2 = w0[o * 6 + 2];
        wa[e][0] = a0; wa[e][1] = a1; wa[e][2] = a2;
        wd[e][0] = w0[o * 6 + 3] - a0;
        wd[e][1] = w0[o * 6 + 4] - a1;
        wd[e][2] = w0[o * 6 + 5] - a2;
        sg[e] = (g[o] >= 0.f) ? 1.f : -1.f;
    }
    float mx[8], sm[8], sq[8];
#pragma unroll
    for (int e = 0; e < 8; ++e) { mx[e] = -3.4e38f; sm[e] = 0.f; sq[e] = 0.f; }
    const int* np = nidx + p * K_;
#pragma unroll 4
    for (int k = 0; k < K_; ++k) {
        int j = bbase + np[k];
        float x0 = x[j * 3], x1 = x[j * 3 + 1], x2 = x[j * 3 + 2];
#pragma unroll
        for (int e = 0; e < 8; ++e) {
            float f = wa[e][0] * x0 + wa[e][1] * x1 + wa[e][2] * x2;
            mx[e] = fmaxf(mx[e], f * sg[e]);
            sm[e] += f;
            sq[e] += f * f;
        }
    }
    float xp0 = x[p * 3], xp1 = x[p * 3 + 1], xp2 = x[p * 3 + 2];
    const float Kf = (float)K_;
    half8v exo;
#pragma unroll
    for (int e = 0; e < 8; ++e) {
        float zf = wd[e][0] * xp0 + wd[e][1] * xp1 + wd[e][2] * xp2;
        exo[e] = (_Float16)(sg[e] * mx[e] + zf);
        s_red[pl * O + v * 8 + e] = sm[e] + Kf * zf;
        q_red[pl * O + v * 8 + e] = sq[e] + 2.f * zf * sm[e] + Kf * zf * zf;
    }
    *(half8v*)&exth[(size_t)p * O + v * 8] = exo;
    __syncthreads();
    int slice = blockIdx.x & 63;
    for (int ch = tid; ch < O; ch += 256) {
        float s = 0.f, q = 0.f;
#pragma unroll
        for (int pp = 0; pp < P; ++pp) { s += s_red[pp * O + ch]; q += q_red[pp * O + ch]; }
        atomicAdd(&psum[slice * 1024 + ch], s);
        atomicAdd(&psq[slice * 1024 + ch], q);
    }
}

// ---------------- gather-reduce + fused BN stats (single extremum, batch-XCD-swizzled) ----------------
template<int O>
__global__ __launch_bounds__(256)
void k_gather(const _Float16* __restrict__ Z, const int* __restrict__ nidx,
              const float* __restrict__ g,
              _Float16* __restrict__ exth,
              float* __restrict__ psum, float* __restrict__ psq) {
    constexpr int VPT = O / 8, P = 256 / VPT;
    __shared__ float s_red[P * O];
    __shared__ float q_red[P * O];
    const int tid = threadIdx.x;
    const int pl = tid / VPT, v = tid % VPT;
    int bsw, local;
    swz_batch(blockIdx.x, bsw, local);
    const int bbase = bsw * N_;
    const int p = bbase + local * P + pl;
    float sg[8];
#pragma unroll
    for (int e = 0; e < 8; ++e) sg[e] = (g[v * 8 + e] >= 0.f) ? 1.f : -1.f;
    float mx[8], sm[8], sq[8];
#pragma unroll
    for (int e = 0; e < 8; ++e) { mx[e] = -3.4e38f; sm[e] = 0.f; sq[e] = 0.f; }
    const int* np = nidx + p * K_;
#pragma unroll 4
    for (int k = 0; k < K_; ++k) {
        int j = np[k];
        half8v z = *(const half8v*)&Z[(size_t)(bbase + j) * (2 * O) + v * 8];
#pragma unroll
        for (int e = 0; e < 8; ++e) {
            float f = (float)z[e];
            mx[e] = fmaxf(mx[e], f * sg[e]);
            sm[e] += f;
            sq[e] += f * f;
        }
    }
    half8v zd = *(const half8v*)&Z[(size_t)p * (2 * O) + O + v * 8];
    const float Kf = (float)K_;
    half8v exo;
#pragma unroll
    for (int e = 0; e < 8; ++e) {
        float zf = (float)zd[e];
        exo[e] = (_Float16)(sg[e] * mx[e] + zf);
        s_red[pl * O + v * 8 + e] = sm[e] + Kf * zf;
        q_red[pl * O + v * 8 + e] = sq[e] + 2.f * zf * sm[e] + Kf * zf * zf;
    }
    *(half8v*)&exth[(size_t)p * O + v * 8] = exo;
    __syncthreads();
    int slice = blockIdx.x & 63;
    for (int ch = tid; ch < O; ch += 256) {
        float s = 0.f, q = 0.f;
#pragma unroll
        for (int pp = 0; pp < P; ++pp) { s += s_red[pp * O + ch]; q += q_red[pp * O + ch]; }
        atomicAdd(&psum[slice * 1024 + ch], s);
        atomicAdd(&psq[slice * 1024 + ch], q);
    }
}

// ---------------- finalize: sum 64 slices -> scale/shift ----------------
__global__ void k_finalize_sl(const float* __restrict__ psum, const float* __restrict__ psq,
                              const float* __restrict__ g, const float* __restrict__ b,
                              float cntInv, int O,
                              float* __restrict__ scale, float* __restrict__ shift) {
    int o = blockIdx.x * 256 + threadIdx.x;
    if (o >= O) return;
    float s = 0.f, q = 0.f;
    for (int i = 0; i < 64; ++i) { s += psum[i * 1024 + o]; q += psq[i * 1024 + o]; }
    float m = s * cntInv;
    float v = q * cntInv - m * m;
    float sc = g[o] * rsqrtf(fmaxf(v, 0.f) + EPSBN);
    scale[o] = sc;
    shift[o] = b[o] - m * sc;
}

// BN + lrelu on selected extremum (fp16 in) -> fp16 cat slice; batch-XCD-swizzled
template<int O>
__global__ void k_bn_apply(const _Float16* __restrict__ exth,
                           const float* __restrict__ scale, const float* __restrict__ shift,
                           _Float16* __restrict__ cath, int coff) {
    constexpr int PPB = 2048 / O;                    // points per block (256 thr x 8 elems)
    int bsw, local;
    swz_batch(blockIdx.x, bsw, local);
    const int pt_base = bsw * N_ + local * PPB;
    int tid = threadIdx.x;
    int pt = pt_base + (tid * 8) / O;
    int v8 = (tid * 8) & (O - 1);
    half8v hx = *(const half8v*)&exth[(size_t)pt * O + v8];
    half8v r;
#pragma unroll
    for (int e = 0; e < 8; ++e) {
        int o = v8 + e;
        float y = scale[o] * (float)hx[e] + shift[o];
        y = y > 0.f ? y : 0.2f * y;
        r[e] = (_Float16)y;
    }
    *(half8v*)&cath[(size_t)pt * 960 + coff + v8] = r;
}

// ---------------- BN+lrelu on Y4 -> fo (B,1024,N f32) transposed + pool partials ----------------
// r9 discovery: old version was ~45us (scalar fp16 loads, 8192 tiny blocks, 1.1 TB/s).
// New: 64x64 tiles (2048 blocks), half8v reads, LDS [64][65] f32 transpose (pad -> 2-way
// bank = free), float4 writes (256B contiguous per 16-lane c-group), shuffle pool partials
// (32 n-tiles per (b,c), no atomics).  Ideal traffic ~50MB -> ~11us.
__global__ __launch_bounds__(256)
void k_feats_out(const _Float16* __restrict__ Y4, const float* __restrict__ scale,
                 const float* __restrict__ shift, float* __restrict__ fo,
                 float* __restrict__ pmax, float* __restrict__ psumn) {
    __shared__ float tile[64][65];
    const int tid = threadIdx.x;
    const int b = blockIdx.z;
    const int n0 = blockIdx.x * 64, c0 = blockIdx.y * 64;
#pragma unroll
    for (int r = 0; r < 2; ++r) {
        int idx = r * 256 + tid;                 // 512 half8 chunks = 64n x 8 c-groups
        int nl = idx >> 3;
        int c8 = (idx & 7) * 8;
        half8v h = *(const half8v*)&Y4[((size_t)(b * N_ + n0 + nl)) * 1024 + c0 + c8];
        float4 s0 = *(const float4*)&scale[c0 + c8];
        float4 s1 = *(const float4*)&scale[c0 + c8 + 4];
        float4 f0 = *(const float4*)&shift[c0 + c8];
        float4 f1 = *(const float4*)&shift[c0 + c8 + 4];
        float y;
        y = s0.x * (float)h[0] + f0.x; tile[nl][c8 + 0] = y > 0.f ? y : 0.2f * y;
        y = s0.y * (float)h[1] + f0.y; tile[nl][c8 + 1] = y > 0.f ? y : 0.2f * y;
        y = s0.z * (float)h[2] + f0.z; tile[nl][c8 + 2] = y > 0.f ? y : 0.2f * y;
        y = s0.w * (float)h[3] + f0.w; tile[nl][c8 + 3] = y > 0.f ? y : 0.2f * y;
        y = s1.x * (float)h[4] + f1.x; tile[nl][c8 + 4] = y > 0.f ? y : 0.2f * y;
        y = s1.y * (float)h[5] + f1.y; tile[nl][c8 + 5] = y > 0.f ? y : 0.2f * y;
        y = s1.z * (float)h[6] + f1.z; tile[nl][c8 + 6] = y > 0.f ? y : 0.2f * y;
        y = s1.w * (float)h[7] + f1.w; tile[nl][c8 + 7] = y > 0.f ? y : 0.2f * y;
    }
    __syncthreads();
#pragma unroll
    for (int r = 0; r < 4; ++r) {
        int idx = r * 256 + tid;                 // 1024 float4 chunks = 64c x 16 n-groups
        int cl = idx >> 4;
        int n4 = (idx & 15) * 4;
        float4 v;
        v.x = tile[n4 + 0][cl];
        v.y = tile[n4 + 1][cl];
        v.z = tile[n4 + 2][cl];
        v.w = tile[n4 + 3][cl];
        *(float4*)&fo[((size_t)(b * 1024 + c0 + cl)) * N_ + n0 + n4] = v;
        float mx = fmaxf(fmaxf(v.x, v.y), fmaxf(v.z, v.w));
        float sm = v.x + v.y + v.z + v.w;
#pragma unroll
        for (int d = 1; d < 16; d <<= 1) {       // reduce the 16-lane group covering 64 n
            mx = fmaxf(mx, __shfl_xor(mx, d));
            sm += __shfl_xor(sm, d);
        }
        if ((tid & 15) == 0) {
            int bc = (b << 10) + c0 + cl;
            pmax[(size_t)bc * 32 + blockIdx.x] = mx;
            psumn[(size_t)bc * 32 + blockIdx.x] = sm;
        }
    }
}

// final pool: per (b,c) reduce 32 tile-partials -> z0 (B,2048) = [max | mean]
__global__ void k_pool2(const float* __restrict__ pmax, const float* __restrict__ psumn,
                        float* __restrict__ z0) {
    int bc = blockIdx.x * 8 + (threadIdx.x >> 5);
    int lane = threadIdx.x & 31;
    float mx = pmax[(size_t)bc * 32 + lane];
    float s  = psumn[(size_t)bc * 32 + lane];
#pragma unroll
    for (int d = 1; d < 32; d <<= 1) {
        mx = fmaxf(mx, __shfl_xor(mx, d));
        s += __shfl_xor(s, d);
    }
    if (lane == 0) {
        int b = bc >> 10, c = bc & 1023;
        z0[b * 2048 + c] = mx;
        z0[b * 2048 + 1024 + c] = s * (1.f / N_);
    }
}

// ---------------- FC: one wave per (batch, output) dot product; optional fused batch-BN+lrelu ----------------
__global__ void k_fc(const float* __restrict__ zin, const float* __restrict__ W,
                     const float* __restrict__ bias,
                     const float* __restrict__ gg, const float* __restrict__ gb,
                     int C, int O, float* __restrict__ zout) {
    __shared__ float sh4[4];
    const int b = threadIdx.x >> 6;
    const int lane = threadIdx.x & 63;
    const int o = blockIdx.x;
    const float* wr = W + (size_t)o * C;
    const float* zr = zin + b * C;
    float s = 0.f;
    for (int c = lane * 4; c < C; c += 256) {
        const float4 wv = *(const float4*)&wr[c];
        const float4 zv = *(const float4*)&zr[c];
        s += wv.x * zv.x + wv.y * zv.y + wv.z * zv.z + wv.w * zv.w;
    }
    s += __shfl_xor(s, 1);
    s += __shfl_xor(s, 2);
    s += __shfl_xor(s, 4);
    s += __shfl_xor(s, 8);
    s += __shfl_xor(s, 16);
    s += __shfl_xor(s, 32);
    if (!gg) {
        if (lane == 0) zout[b * O + o] = s + (bias ? bias[o] : 0.f);
        return;
    }
    if (lane == 0) sh4[b] = s + (bias ? bias[o] : 0.f);
    __syncthreads();
    if (threadIdx.x == 0) {
        float v0 = sh4[0], v1 = sh4[1], v2 = sh4[2], v3 = sh4[3];
        float m = 0.25f * (v0 + v1 + v2 + v3);
        float d0 = v0 - m, d1 = v1 - m, d2 = v2 - m, d3 = v3 - m;
        float var = 0.25f * (d0 * d0 + d1 * d1 + d2 * d2 + d3 * d3);
        float sc = gg[o] * rsqrtf(var + EPSBN);
        float shv = gb[o];
        float r0 = sc * d0 + shv, r1 = sc * d1 + shv, r2 = sc * d2 + shv, r3 = sc * d3 + shv;
        zout[o]         = r0 > 0.f ? r0 : 0.2f * r0;
        zout[O + o]     = r1 > 0.f ? r1 : 0.2f * r1;
        zout[2 * O + o] = r2 > 0.f ? r2 : 0.2f * r2;
        zout[3 * O + o] = r3 > 0.f ? r3 : 0.2f * r3;
    }
}

// ---------------- launch ----------------

extern "C" void kernel_launch(void* const* d_in, const int* in_sizes, int n_in,
                              void* d_out, int out_size, void* d_ws, size_t ws_size,
                              hipStream_t stream) {
    const float* x    = (const float*)d_in[0];
    const int*   nidx = (const int*)d_in[1];
    const float* w[5]  = {(const float*)d_in[2], (const float*)d_in[5], (const float*)d_in[8],
                          (const float*)d_in[11], (const float*)d_in[14]};
    const float* g[5]  = {(const float*)d_in[3], (const float*)d_in[6], (const float*)d_in[9],
                          (const float*)d_in[12], (const float*)d_in[15]};
    const float* bb[5] = {(const float*)d_in[4], (const float*)d_in[7], (const float*)d_in[10],
                          (const float*)d_in[13], (const float*)d_in[16]};
    const float* lw1 = (const float*)d_in[17];
    const float* g6  = (const float*)d_in[18];
    const float* b6  = (const float*)d_in[19];
    const float* lw2 = (const float*)d_in[20];
    const float* lb2 = (const float*)d_in[21];
    const float* g7  = (const float*)d_in[22];
    const float* b7  = (const float*)d_in[23];
    const float* lw3 = (const float*)d_in[24];
    const float* lb3 = (const float*)d_in[25];

    float* out = (float*)d_out;
    float* fo  = out + 1024;              // feats (B,1024,N)

    uint8_t* base8 = (uint8_t*)d_ws;
    size_t off = 0;
    auto alloc = [&](size_t bytes) -> void* {
        void* r = base8 + off;
        off += (bytes + 255) & ~(size_t)255;
        return r;
    };
    _Float16* cath = (_Float16*)alloc((size_t)B_ * N_ * 960 * 2);   // 15.7 MB
    _Float16* Z    = (_Float16*)alloc((size_t)8192 * 1024 * 2);     // 16.8 MB
    _Float16* exth = (_Float16*)alloc((size_t)8192 * 512 * 2);      // 8.4 MB
    _Float16* Y4   = (_Float16*)alloc((size_t)8192 * 1024 * 2);     // 16.8 MB
    _Float16* W2h1 = (_Float16*)alloc((size_t)256 * 64 * 2);
    _Float16* W2h2 = (_Float16*)alloc((size_t)512 * 128 * 2);
    _Float16* W2h3 = (_Float16*)alloc((size_t)1024 * 256 * 2);
    _Float16* w4h  = (_Float16*)alloc((size_t)1024 * 960 * 2);
    float* psumall = (float*)alloc((size_t)5 * 131072 * 4);         // 2.6 MB, 5 regions
    float* pmax  = (float*)alloc((size_t)4096 * 32 * 4);            // 512 KB
    float* psumn = (float*)alloc((size_t)4096 * 32 * 4);            // 512 KB
    float* scalev= (float*)alloc(1024 * 4);
    float* shiftv= (float*)alloc(1024 * 4);
    float* z0    = (float*)alloc(8192 * 4);
    float* z1    = (float*)alloc(4096 * 4);
    float* z2    = (float*)alloc(2048 * 4);
    (void)ws_size; (void)in_sizes; (void)n_in; (void)out_size;

    auto psumR = [&](int r) { return psumall + (size_t)r * 131072; };
    auto psqR  = [&](int r) { return psumall + (size_t)r * 131072 + 65536; };

    // one upfront zero of all stat regions + one fused weight-prep launch
    hipMemsetAsync(psumall, 0, (size_t)5 * 131072 * 4, stream);
    k_prep_all<<<(8192 + 32768 + 131072 + 983040 + 255) / 256, 256, 0, stream>>>(
        w[1], w[2], w[3], w[4], W2h1, W2h2, W2h3, w4h);

    // ---- layer 0 (C=3 -> O=64): fused dense + gather (no Z0 round-trip) ----
    k_gather0<<<256, 256, 0, stream>>>(x, w[0], nidx, g[0], exth, psumR(0), psqR(0));
    k_finalize_sl<<<1, 256, 0, stream>>>(psumR(0), psqR(0), g[0], bb[0], 1.f / (B_ * N_ * K_),
                                         64, scalev, shiftv);
    k_bn_apply<64><<<256, 256, 0, stream>>>(exth, scalev, shiftv, cath, 0);

    // ---- layers 1-3: dense MFMA GEMM + fused gather ----
    k_gemm<false, 64><<<dim3(128, 2), 256, 0, stream>>>(cath + 0, 960, W2h1, 64,
                                                        Z, 256, nullptr, nullptr);
    k_gather<128><<<512, 256, 0, stream>>>(Z, nidx, g[1], exth, psumR(1), psqR(1));
    k_finalize_sl<<<1, 256, 0, stream>>>(psumR(1), psqR(1), g[1], bb[1],
                                         1.f / (B_ * N_ * K_), 128, scalev, shiftv);
    k_bn_apply<128><<<512, 256, 0, stream>>>(exth, scalev, shiftv, cath, 64);

    k_gemm<false, 128><<<dim3(64, 4), 256, 0, stream>>>(cath + 64, 960, W2h2, 128,
                                                        Z, 512, nullptr, nullptr);
    k_gather<256><<<1024, 256, 0, stream>>>(Z, nidx, g[2], exth, psumR(2), psqR(2));
    k_finalize_sl<<<1, 256, 0, stream>>>(psumR(2), psqR(2), g[2], bb[2],
                                         1.f / (B_ * N_ * K_), 256, scalev, shiftv);
    k_bn_apply<256><<<1024, 256, 0, stream>>>(exth, scalev, shiftv, cath, 192);

    k_gemm<false, 128><<<dim3(64, 8), 256, 0, stream>>>(cath + 192, 960, W2h3, 256,
                                                        Z, 1024, nullptr, nullptr);
    k_gather<512><<<2048, 256, 0, stream>>>(Z, nidx, g[3], exth, psumR(3), psqR(3));
    k_finalize_sl<<<2, 256, 0, stream>>>(psumR(3), psqR(3), g[3], bb[3],
                                         1.f / (B_ * N_ * K_), 512, scalev, shiftv);
    k_bn_apply<512><<<2048, 256, 0, stream>>>(exth, scalev, shiftv, cath, 448);

    // ---- feats = lrelu(bn(w4 @ cat)) with fused column stats ----
    k_gemm<true, 128><<<dim3(64, 8), 256, 0, stream>>>(cath, 960, w4h, 960, Y4, 1024,
                                                       psumR(4), psqR(4));
    k_finalize_sl<<<4, 256, 0, stream>>>(psumR(4), psqR(4), g[4], bb[4], 1.f / (B_ * N_), 1024,
                                         scalev, shiftv);
    k_feats_out<<<dim3(32, 16, 4), 256, 0, stream>>>(Y4, scalev, shiftv, fo, pmax, psumn);
    k_pool2<<<512, 256, 0, stream>>>(pmax, psumn, z0);

    // ---- FC head (BN fused into FC blocks) ----
    k_fc<<<1024, 256, 0, stream>>>(z0, lw1, nullptr, g6, b6, 2048, 1024, z1);
    k_fc<<<512, 256, 0, stream>>>(z1, lw2, lb2, g7, b7, 1024, 512, z2);
    k_fc<<<256, 256, 0, stream>>>(z2, lw3, lb3, nullptr, nullptr, 512, 256, out);
}

// Round 11
// 146.731 us; speedup vs baseline: 1.2012x; 1.1103x over previous
//
#include <hip/hip_runtime.h>
#include <cstddef>
#include <cstdint>

#define EPSBN 1e-5f
constexpr int B_ = 4, N_ = 2048, K_ = 20;

typedef __attribute__((ext_vector_type(8))) _Float16 half8v;
typedef __attribute__((ext_vector_type(4))) float f32x4;
typedef const __attribute__((address_space(1))) unsigned int* gas_t;
typedef __attribute__((address_space(3))) unsigned int* las_t;

// batch-XCD swizzle: block B -> (batch, local) with B&7 = XCD slot, batch b on slots {2b,2b+1}
__device__ __forceinline__ void swz_batch(int B, int& b, int& local) {
    b = (B & 7) >> 1;
    local = ((B >> 3) << 1) | (B & 1);
}

// ---------------- fused weight prep (layers 1-3 conv + w4 cast) ----------------

__device__ __forceinline__ void prep_conv(const float* __restrict__ W, _Float16* __restrict__ W2h,
                                          int O, int C, int i) {
    int o = i / C, c = i - o * C;
    float a = W[o * 2 * C + c];
    float d = W[o * 2 * C + C + c] - a;
    W2h[(size_t)o * C + c] = (_Float16)a;
    W2h[(size_t)(O + o) * C + c] = (_Float16)d;
}

__global__ void k_prep_all(const float* __restrict__ w1, const float* __restrict__ w2,
                           const float* __restrict__ w3, const float* __restrict__ w4,
                           _Float16* __restrict__ W2h1, _Float16* __restrict__ W2h2,
                           _Float16* __restrict__ W2h3, _Float16* __restrict__ w4h) {
    int i = blockIdx.x * 256 + threadIdx.x;
    if (i < 8192) { prep_conv(w1, W2h1, 128, 64, i); return; }
    i -= 8192;
    if (i < 32768) { prep_conv(w2, W2h2, 256, 128, i); return; }
    i -= 32768;
    if (i < 131072) { prep_conv(w3, W2h3, 512, 256, i); return; }
    i -= 131072;
    if (i < 983040) w4h[i] = (_Float16)w4[i];
}

// ---------------- generic MFMA GEMM: out(fp16) = A (8192 x K, stride sa) @ Bw^T ----------------
// BM x 128 tile; 4 waves x ((BM/2) x 64); global_load_lds staging, XOR-swizzled LDS,
// single-buffer (r4/r5/r7: pipelining & in-GEMM transforms all neutral-to-negative).
template<bool STATS, int BM>
__global__ __launch_bounds__(256, 3)
void k_gemm(const _Float16* __restrict__ A, int sa,
            const _Float16* __restrict__ Bw, int K,
            _Float16* __restrict__ outp, int so,
            float* __restrict__ psum, float* __restrict__ psq) {
    constexpr int MI = BM / 32;
    __shared__ __align__(16) _Float16 Als[BM * 64];
    __shared__ __align__(16) _Float16 Bls[128 * 64];
    const int tid = threadIdx.x, lane = tid & 63, w = tid >> 6;
    int bsw, lsw;
    swz_batch(blockIdx.x, bsw, lsw);
    constexpr int TPB = 2048 / BM;
    const int m0 = (bsw * TPB + lsw) * BM;
    const int n0 = blockIdx.y * 128;
    const int wr = (w >> 1) * (BM / 2), wc = (w & 1) * 64;

    f32x4 acc[MI][4];
#pragma unroll
    for (int i = 0; i < MI; ++i)
#pragma unroll
        for (int j = 0; j < 4; ++j) acc[i][j] = (f32x4){0.f, 0.f, 0.f, 0.f};

    int srb[4], scb[4];
#pragma unroll
    for (int j = 0; j < 4; ++j) {
        int idx = w * 256 + j * 64 + lane;
        srb[j] = idx >> 3;
        scb[j] = ((idx & 7) ^ (srb[j] & 7)) * 8;
    }
    int sra[MI], sca[MI];
#pragma unroll
    for (int j = 0; j < MI; ++j) {
        int idx = w * (MI * 64) + j * 64 + lane;
        sra[j] = idx >> 3;
        sca[j] = ((idx & 7) ^ (sra[j] & 7)) * 8;
    }
    int aoff[MI][2], boff[4][2];
#pragma unroll
    for (int i = 0; i < MI; ++i) {
        int ra = wr + i * 16 + (lane & 15);
#pragma unroll
        for (int t = 0; t < 2; ++t)
            aoff[i][t] = ra * 64 + ((((lane >> 4) + t * 4) ^ (ra & 7)) * 8);
    }
#pragma unroll
    for (int j = 0; j < 4; ++j) {
        int rb = wc + j * 16 + (lane & 15);
#pragma unroll
        for (int t = 0; t < 2; ++t)
            boff[j][t] = rb * 64 + ((((lane >> 4) + t * 4) ^ (rb & 7)) * 8);
    }

    for (int c0 = 0; c0 < K; c0 += 64) {
#pragma unroll
        for (int j = 0; j < MI; ++j) {
            const _Float16* ga = &A[(size_t)(m0 + sra[j]) * sa + c0 + sca[j]];
            __builtin_amdgcn_global_load_lds((gas_t)(const void*)ga,
                                             (las_t)(void*)&Als[(w * MI * 64 + j * 64) * 8], 16, 0, 0);
        }
#pragma unroll
        for (int j = 0; j < 4; ++j) {
            const _Float16* gb = &Bw[(size_t)(n0 + srb[j]) * K + c0 + scb[j]];
            __builtin_amdgcn_global_load_lds((gas_t)(const void*)gb,
                                             (las_t)(void*)&Bls[(w * 256 + j * 64) * 8], 16, 0, 0);
        }
        __syncthreads();
#pragma unroll
        for (int t = 0; t < 2; ++t) {
            half8v a[MI], b[4];
#pragma unroll
            for (int i = 0; i < MI; ++i) a[i] = *(const half8v*)&Als[aoff[i][t]];
#pragma unroll
            for (int j = 0; j < 4; ++j) b[j] = *(const half8v*)&Bls[boff[j][t]];
#pragma unroll
            for (int i = 0; i < MI; ++i)
#pragma unroll
                for (int j = 0; j < 4; ++j)
                    acc[i][j] = __builtin_amdgcn_mfma_f32_16x16x32_f16(a[i], b[j], acc[i][j], 0, 0, 0);
        }
        __syncthreads();
    }
#pragma unroll
    for (int i = 0; i < MI; ++i)
#pragma unroll
        for (int j = 0; j < 4; ++j)
#pragma unroll
            for (int e = 0; e < 4; ++e) {
                int row = m0 + wr + i * 16 + (lane >> 4) * 4 + e;
                int col = n0 + wc + j * 16 + (lane & 15);
                outp[(size_t)row * so + col] = (_Float16)acc[i][j][e];
            }
    if constexpr (STATS) {
        int slice = blockIdx.x & 63;
#pragma unroll
        for (int j = 0; j < 4; ++j) {
            float s = 0.f, q = 0.f;
#pragma unroll
            for (int i = 0; i < MI; ++i)
#pragma unroll
                for (int e = 0; e < 4; ++e) {
                    float v = acc[i][j][e];
                    s += v; q += v * v;
                }
            s += __shfl_xor(s, 16); s += __shfl_xor(s, 32);
            q += __shfl_xor(q, 16); q += __shfl_xor(q, 32);
            if ((lane >> 4) == 0) {
                int col = n0 + wc + j * 16 + lane;
                atomicAdd(&psum[slice * 1024 + col], s);
                atomicAdd(&psq[slice * 1024 + col], q);
            }
        }
    }
}

// ---------------- layer-0: fused dense (C=3) + gather-reduce + BN stats ----------------
__global__ __launch_bounds__(256)
void k_gather0(const float* __restrict__ x, const float* __restrict__ w0,
               const int* __restrict__ nidx, const float* __restrict__ g,
               _Float16* __restrict__ exth,
               float* __restrict__ psum, float* __restrict__ psq) {
    constexpr int O = 64, VPT = 8, P = 32;
    __shared__ float s_red[P * O];
    __shared__ float q_red[P * O];
    const int tid = threadIdx.x;
    const int pl = tid / VPT, v = tid % VPT;
    int bsw, local;
    swz_batch(blockIdx.x, bsw, local);
    const int bbase = bsw * N_;
    const int p = bbase + local * P + pl;
    float wa[8][3], wd[8][3], sg[8];
#pragma unroll
    for (int e = 0; e < 8; ++e) {
        int o = v * 8 + e;
        float a0 = w0[o * 6], a1 = w0[o * 6 + 1], a2 = w0[o * 6 + 2];
        wa[e][0] = a0; wa[e][1] = a1; wa[e][2] = a2;
        wd[e][0] = w0[o * 6 + 3] - a0;
        wd[e][1] = w0[o * 6 + 4] - a1;
        wd[e][2] = w0[o * 6 + 5] - a2;
        sg[e] = (g[o] >= 0.f) ? 1.f : -1.f;
    }
    float mx[8], sm[8], sq[8];
#pragma unroll
    for (int e = 0; e < 8; ++e) { mx[e] = -3.4e38f; sm[e] = 0.f; sq[e] = 0.f; }
    const int* np = nidx + p * K_;
#pragma unroll 4
    for (int k = 0; k < K_; ++k) {
        int j = bbase + np[k];
        float x0 = x[j * 3], x1 = x[j * 3 + 1], x2 = x[j * 3 + 2];
#pragma unroll
        for (int e = 0; e < 8; ++e) {
            float f = wa[e][0] * x0 + wa[e][1] * x1 + wa[e][2] * x2;
            mx[e] = fmaxf(mx[e], f * sg[e]);
            sm[e] += f;
            sq[e] += f * f;
        }
    }
    float xp0 = x[p * 3], xp1 = x[p * 3 + 1], xp2 = x[p * 3 + 2];
    const float Kf = (float)K_;
    half8v exo;
#pragma unroll
    for (int e = 0; e < 8; ++e) {
        float zf = wd[e][0] * xp0 + wd[e][1] * xp1 + wd[e][2] * xp2;
        exo[e] = (_Float16)(sg[e] * mx[e] + zf);
        s_red[pl * O + v * 8 + e] = sm[e] + Kf * zf;
        q_red[pl * O + v * 8 + e] = sq[e] + 2.f * zf * sm[e] + Kf * zf * zf;
    }
    *(half8v*)&exth[(size_t)p * O + v * 8] = exo;
    __syncthreads();
    int slice = blockIdx.x & 63;
    for (int ch = tid; ch < O; ch += 256) {
        float s = 0.f, q = 0.f;
#pragma unroll
        for (int pp = 0; pp < P; ++pp) { s += s_red[pp * O + ch]; q += q_red[pp * O + ch]; }
        atomicAdd(&psum[slice * 1024 + ch], s);
        atomicAdd(&psq[slice * 1024 + ch], q);
    }
}

// ---------------- gather-reduce + fused BN stats (single extremum, batch-XCD-swizzled) ----------------
template<int O>
__global__ __launch_bounds__(256)
void k_gather(const _Float16* __restrict__ Z, const int* __restrict__ nidx,
              const float* __restrict__ g,
              _Float16* __restrict__ exth,
              float* __restrict__ psum, float* __restrict__ psq) {
    constexpr int VPT = O / 8, P = 256 / VPT;
    __shared__ float s_red[P * O];
    __shared__ float q_red[P * O];
    const int tid = threadIdx.x;
    const int pl = tid / VPT, v = tid % VPT;
    int bsw, local;
    swz_batch(blockIdx.x, bsw, local);
    const int bbase = bsw * N_;
    const int p = bbase + local * P + pl;
    float sg[8];
#pragma unroll
    for (int e = 0; e < 8; ++e) sg[e] = (g[v * 8 + e] >= 0.f) ? 1.f : -1.f;
    float mx[8], sm[8], sq[8];
#pragma unroll
    for (int e = 0; e < 8; ++e) { mx[e] = -3.4e38f; sm[e] = 0.f; sq[e] = 0.f; }
    const int* np = nidx + p * K_;
#pragma unroll 4
    for (int k = 0; k < K_; ++k) {
        int j = np[k];
        half8v z = *(const half8v*)&Z[(size_t)(bbase + j) * (2 * O) + v * 8];
#pragma unroll
        for (int e = 0; e < 8; ++e) {
            float f = (float)z[e];
            mx[e] = fmaxf(mx[e], f * sg[e]);
            sm[e] += f;
            sq[e] += f * f;
        }
    }
    half8v zd = *(const half8v*)&Z[(size_t)p * (2 * O) + O + v * 8];
    const float Kf = (float)K_;
    half8v exo;
#pragma unroll
    for (int e = 0; e < 8; ++e) {
        float zf = (float)zd[e];
        exo[e] = (_Float16)(sg[e] * mx[e] + zf);
        s_red[pl * O + v * 8 + e] = sm[e] + Kf * zf;
        q_red[pl * O + v * 8 + e] = sq[e] + 2.f * zf * sm[e] + Kf * zf * zf;
    }
    *(half8v*)&exth[(size_t)p * O + v * 8] = exo;
    __syncthreads();
    int slice = blockIdx.x & 63;
    for (int ch = tid; ch < O; ch += 256) {
        float s = 0.f, q = 0.f;
#pragma unroll
        for (int pp = 0; pp < P; ++pp) { s += s_red[pp * O + ch]; q += q_red[pp * O + ch]; }
        atomicAdd(&psum[slice * 1024 + ch], s);
        atomicAdd(&psq[slice * 1024 + ch], q);
    }
}

// ---------------- fused finalize + BN-apply (re-landed from r9, verified there) ----------------
// Each block: (128-point tile) x (64-channel tile).  Phase 1: reduce the 64 stat slices
// for ITS 64 channels only into LDS scale/shift (cheap, unlike r7's per-N-tile redundancy).
// Phase 2: apply BN+lrelu to its 128x64 slab exth -> cath.  Stats are device-scope atomics
// completed at producer kernel boundary -> visible, no fence.
template<int O>
__global__ __launch_bounds__(256)
void k_bnfin(const _Float16* __restrict__ exth,
             const float* __restrict__ psum, const float* __restrict__ psq,
             const float* __restrict__ g, const float* __restrict__ b, float cntInv,
             _Float16* __restrict__ cath, int coff) {
    constexpr int NCT = O / 64;                      // channel tiles
    __shared__ float part_s[64][4];
    __shared__ float part_q[64][4];
    __shared__ float scale_s[64], shift_s[64];
    const int tid = threadIdx.x;
    const int ct = blockIdx.x % NCT;
    const int ptile = blockIdx.x / NCT;              // [0,64)
    int bsw, local;
    swz_batch(ptile, bsw, local);                    // local in [0,16)
    const int ch0 = ct * 64;
    {   // phase 1: per-channel slice reduction (4 threads/channel, 16 slices each)
        int lc = tid >> 2, q = tid & 3;
        int ch = ch0 + lc;
        float s = 0.f, qq = 0.f;
        for (int i = q * 16; i < q * 16 + 16; ++i) {
            s += psum[i * 1024 + ch];
            qq += psq[i * 1024 + ch];
        }
        part_s[lc][q] = s; part_q[lc][q] = qq;
    }
    __syncthreads();
    if ((tid & 3) == 0) {
        int lc = tid >> 2;
        float s = part_s[lc][0] + part_s[lc][1] + part_s[lc][2] + part_s[lc][3];
        float qq = part_q[lc][0] + part_q[lc][1] + part_q[lc][2] + part_q[lc][3];
        float m = s * cntInv;
        float v = qq * cntInv - m * m;
        float sc = g[ch0 + lc] * rsqrtf(fmaxf(v, 0.f) + EPSBN);
        scale_s[lc] = sc;
        shift_s[lc] = b[ch0 + lc] - m * sc;
    }
    __syncthreads();
    // phase 2: apply to 128 points x 64 channels
    const int pbase = bsw * N_ + local * 128;
#pragma unroll
    for (int r = 0; r < 4; ++r) {
        int idx = r * 256 + tid;
        int ptl = idx >> 3;                          // [0,128)
        int cb = (idx & 7) * 8;                      // [0,64) in steps of 8
        int p = pbase + ptl;
        half8v hx = *(const half8v*)&exth[(size_t)p * O + ch0 + cb];
        half8v rr;
#pragma unroll
        for (int e = 0; e < 8; ++e) {
            float y = scale_s[cb + e] * (float)hx[e] + shift_s[cb + e];
            rr[e] = (_Float16)(y > 0.f ? y : 0.2f * y);
        }
        *(half8v*)&cath[(size_t)p * 960 + coff + ch0 + cb] = rr;
    }
}

// ---------------- BN+lrelu on Y4 -> fo (B,1024,N f32) transposed + pool partials ----------------
// r10's vectorized 64x64-tile version, extended with:
//  * phase 0: in-kernel finalize of the w4 BN scale/shift for this block's 64-channel tile
//    (same verified pattern as k_bnfin phase 1) -- kills the k_finalize_sl<4> dispatch.
//  * XCD-aligned 1-D decode: G4 wrote Y4 rows for (batch b, 128-row tile l) on XCD slot
//    2b|(l&1); we pick (b, n-tile, c-tile) so this block reads Y4 from its own XCD's L2.
__global__ __launch_bounds__(256)
void k_feats_out(const _Float16* __restrict__ Y4,
                 const float* __restrict__ psum, const float* __restrict__ psq,
                 const float* __restrict__ g, const float* __restrict__ bv,
                 float* __restrict__ fo,
                 float* __restrict__ pmax, float* __restrict__ psumn) {
    __shared__ float tile[64][65];
    __shared__ float part_s[64][4];
    __shared__ float part_q[64][4];
    __shared__ float scale_s[64], shift_s[64];
    const int tid = threadIdx.x;
    // decode: slot = id&7 -> b = slot>>1, parity = slot&1; nx chosen so (nx>>1)&1 == parity
    const int id = blockIdx.x;
    const int b = (id & 7) >> 1, par = id & 1;
    const int local = id >> 3;                       // [0,256)
    const int cy = local >> 4;                       // [0,16) c-tile
    const int k = local & 15;
    const int nx = ((k >> 1) << 2) | (par << 1) | (k & 1);   // [0,32), slot-parity matched
    const int n0 = nx * 64, c0 = cy * 64;
    // ---- phase 0: finalize BN scale/shift for this 64-channel tile ----
    {
        int lc = tid >> 2, q = tid & 3;
        int ch = c0 + lc;
        float s = 0.f, qq = 0.f;
        for (int i = q * 16; i < q * 16 + 16; ++i) {
            s += psum[i * 1024 + ch];
            qq += psq[i * 1024 + ch];
        }
        part_s[lc][q] = s; part_q[lc][q] = qq;
    }
    __syncthreads();
    if ((tid & 3) == 0) {
        int lc = tid >> 2;
        const float cntInv = 1.f / (B_ * N_);
        float s = part_s[lc][0] + part_s[lc][1] + part_s[lc][2] + part_s[lc][3];
        float qq = part_q[lc][0] + part_q[lc][1] + part_q[lc][2] + part_q[lc][3];
        float m = s * cntInv;
        float v = qq * cntInv - m * m;
        float sc = g[c0 + lc] * rsqrtf(fmaxf(v, 0.f) + EPSBN);
        scale_s[lc] = sc;
        shift_s[lc] = bv[c0 + lc] - m * sc;
    }
    __syncthreads();
    // ---- phase 1: vectorized load + BN + lrelu into LDS transpose tile ----
#pragma unroll
    for (int r = 0; r < 2; ++r) {
        int idx = r * 256 + tid;                 // 512 half8 chunks = 64n x 8 c-groups
        int nl = idx >> 3;
        int c8 = (idx & 7) * 8;
        half8v h = *(const half8v*)&Y4[((size_t)(b * N_ + n0 + nl)) * 1024 + c0 + c8];
#pragma unroll
        for (int e = 0; e < 8; ++e) {
            float y = scale_s[c8 + e] * (float)h[e] + shift_s[c8 + e];
            tile[nl][c8 + e] = y > 0.f ? y : 0.2f * y;
        }
    }
    __syncthreads();
    // ---- phase 2: transposed float4 stores + pool partials ----
#pragma unroll
    for (int r = 0; r < 4; ++r) {
        int idx = r * 256 + tid;                 // 1024 float4 chunks = 64c x 16 n-groups
        int cl = idx >> 4;
        int n4 = (idx & 15) * 4;
        float4 v;
        v.x = tile[n4 + 0][cl];
        v.y = tile[n4 + 1][cl];
        v.z = tile[n4 + 2][cl];
        v.w = tile[n4 + 3][cl];
        *(float4*)&fo[((size_t)(b * 1024 + c0 + cl)) * N_ + n0 + n4] = v;
        float mx = fmaxf(fmaxf(v.x, v.y), fmaxf(v.z, v.w));
        float sm = v.x + v.y + v.z + v.w;
#pragma unroll
        for (int d = 1; d < 16; d <<= 1) {       // reduce the 16-lane group covering 64 n
            mx = fmaxf(mx, __shfl_xor(mx, d));
            sm += __shfl_xor(sm, d);
        }
        if ((tid & 15) == 0) {
            int bc = (b << 10) + c0 + cl;
            pmax[(size_t)bc * 32 + nx] = mx;
            psumn[(size_t)bc * 32 + nx] = sm;
        }
    }
}

// final pool: per (b,c) reduce 32 tile-partials -> z0 (B,2048) = [max | mean]
__global__ void k_pool2(const float* __restrict__ pmax, const float* __restrict__ psumn,
                        float* __restrict__ z0) {
    int bc = blockIdx.x * 8 + (threadIdx.x >> 5);
    int lane = threadIdx.x & 31;
    float mx = pmax[(size_t)bc * 32 + lane];
    float s  = psumn[(size_t)bc * 32 + lane];
#pragma unroll
    for (int d = 1; d < 32; d <<= 1) {
        mx = fmaxf(mx, __shfl_xor(mx, d));
        s += __shfl_xor(s, d);
    }
    if (lane == 0) {
        int b = bc >> 10, c = bc & 1023;
        z0[b * 2048 + c] = mx;
        z0[b * 2048 + 1024 + c] = s * (1.f / N_);
    }
}

// ---------------- FC: one wave per (batch, output) dot product; optional fused batch-BN+lrelu ----------------
__global__ void k_fc(const float* __restrict__ zin, const float* __restrict__ W,
                     const float* __restrict__ bias,
                     const float* __restrict__ gg, const float* __restrict__ gb,
                     int C, int O, float* __restrict__ zout) {
    __shared__ float sh4[4];
    const int b = threadIdx.x >> 6;
    const int lane = threadIdx.x & 63;
    const int o = blockIdx.x;
    const float* wr = W + (size_t)o * C;
    const float* zr = zin + b * C;
    float s = 0.f;
    for (int c = lane * 4; c < C; c += 256) {
        const float4 wv = *(const float4*)&wr[c];
        const float4 zv = *(const float4*)&zr[c];
        s += wv.x * zv.x + wv.y * zv.y + wv.z * zv.z + wv.w * zv.w;
    }
    s += __shfl_xor(s, 1);
    s += __shfl_xor(s, 2);
    s += __shfl_xor(s, 4);
    s += __shfl_xor(s, 8);
    s += __shfl_xor(s, 16);
    s += __shfl_xor(s, 32);
    if (!gg) {
        if (lane == 0) zout[b * O + o] = s + (bias ? bias[o] : 0.f);
        return;
    }
    if (lane == 0) sh4[b] = s + (bias ? bias[o] : 0.f);
    __syncthreads();
    if (threadIdx.x == 0) {
        float v0 = sh4[0], v1 = sh4[1], v2 = sh4[2], v3 = sh4[3];
        float m = 0.25f * (v0 + v1 + v2 + v3);
        float d0 = v0 - m, d1 = v1 - m, d2 = v2 - m, d3 = v3 - m;
        float var = 0.25f * (d0 * d0 + d1 * d1 + d2 * d2 + d3 * d3);
        float sc = gg[o] * rsqrtf(var + EPSBN);
        float shv = gb[o];
        float r0 = sc * d0 + shv, r1 = sc * d1 + shv, r2 = sc * d2 + shv, r3 = sc * d3 + shv;
        zout[o]         = r0 > 0.f ? r0 : 0.2f * r0;
        zout[O + o]     = r1 > 0.f ? r1 : 0.2f * r1;
        zout[2 * O + o] = r2 > 0.f ? r2 : 0.2f * r2;
        zout[3 * O + o] = r3 > 0.f ? r3 : 0.2f * r3;
    }
}

// ---------------- launch ----------------

extern "C" void kernel_launch(void* const* d_in, const int* in_sizes, int n_in,
                              void* d_out, int out_size, void* d_ws, size_t ws_size,
                              hipStream_t stream) {
    const float* x    = (const float*)d_in[0];
    const int*   nidx = (const int*)d_in[1];
    const float* w[5]  = {(const float*)d_in[2], (const float*)d_in[5], (const float*)d_in[8],
                          (const float*)d_in[11], (const float*)d_in[14]};
    const float* g[5]  = {(const float*)d_in[3], (const float*)d_in[6], (const float*)d_in[9],
                          (const float*)d_in[12], (const float*)d_in[15]};
    const float* bb[5] = {(const float*)d_in[4], (const float*)d_in[7], (const float*)d_in[10],
                          (const float*)d_in[13], (const float*)d_in[16]};
    const float* lw1 = (const float*)d_in[17];
    const float* g6  = (const float*)d_in[18];
    const float* b6  = (const float*)d_in[19];
    const float* lw2 = (const float*)d_in[20];
    const float* lb2 = (const float*)d_in[21];
    const float* g7  = (const float*)d_in[22];
    const float* b7  = (const float*)d_in[23];
    const float* lw3 = (const float*)d_in[24];
    const float* lb3 = (const float*)d_in[25];

    float* out = (float*)d_out;
    float* fo  = out + 1024;              // feats (B,1024,N)

    uint8_t* base8 = (uint8_t*)d_ws;
    size_t off = 0;
    auto alloc = [&](size_t bytes) -> void* {
        void* r = base8 + off;
        off += (bytes + 255) & ~(size_t)255;
        return r;
    };
    _Float16* cath = (_Float16*)alloc((size_t)B_ * N_ * 960 * 2);   // 15.7 MB
    _Float16* Z    = (_Float16*)alloc((size_t)8192 * 1024 * 2);     // 16.8 MB
    _Float16* exth = (_Float16*)alloc((size_t)8192 * 512 * 2);      // 8.4 MB
    _Float16* Y4   = (_Float16*)alloc((size_t)8192 * 1024 * 2);     // 16.8 MB
    _Float16* W2h1 = (_Float16*)alloc((size_t)256 * 64 * 2);
    _Float16* W2h2 = (_Float16*)alloc((size_t)512 * 128 * 2);
    _Float16* W2h3 = (_Float16*)alloc((size_t)1024 * 256 * 2);
    _Float16* w4h  = (_Float16*)alloc((size_t)1024 * 960 * 2);
    float* psumall = (float*)alloc((size_t)5 * 131072 * 4);         // 2.6 MB, 5 regions
    float* pmax  = (float*)alloc((size_t)4096 * 32 * 4);            // 512 KB
    float* psumn = (float*)alloc((size_t)4096 * 32 * 4);            // 512 KB
    float* z0    = (float*)alloc(8192 * 4);
    float* z1    = (float*)alloc(4096 * 4);
    float* z2    = (float*)alloc(2048 * 4);
    (void)ws_size; (void)in_sizes; (void)n_in; (void)out_size;

    auto psumR = [&](int r) { return psumall + (size_t)r * 131072; };
    auto psqR  = [&](int r) { return psumall + (size_t)r * 131072 + 65536; };

    // one upfront zero of all stat regions + one fused weight-prep launch
    hipMemsetAsync(psumall, 0, (size_t)5 * 131072 * 4, stream);
    k_prep_all<<<(8192 + 32768 + 131072 + 983040 + 255) / 256, 256, 0, stream>>>(
        w[1], w[2], w[3], w[4], W2h1, W2h2, W2h3, w4h);

    const float invK = 1.f / (B_ * N_ * K_);

    // ---- layer 0 (C=3 -> O=64): fused dense + gather, then fused finalize+BN ----
    k_gather0<<<256, 256, 0, stream>>>(x, w[0], nidx, g[0], exth, psumR(0), psqR(0));
    k_bnfin<64><<<64, 256, 0, stream>>>(exth, psumR(0), psqR(0), g[0], bb[0], invK, cath, 0);

    // ---- layers 1-3: dense MFMA GEMM + fused gather + fused finalize+BN ----
    k_gemm<false, 64><<<dim3(128, 2), 256, 0, stream>>>(cath + 0, 960, W2h1, 64,
                                                        Z, 256, nullptr, nullptr);
    k_gather<128><<<512, 256, 0, stream>>>(Z, nidx, g[1], exth, psumR(1), psqR(1));
    k_bnfin<128><<<128, 256, 0, stream>>>(exth, psumR(1), psqR(1), g[1], bb[1], invK, cath, 64);

    k_gemm<false, 128><<<dim3(64, 4), 256, 0, stream>>>(cath + 64, 960, W2h2, 128,
                                                        Z, 512, nullptr, nullptr);
    k_gather<256><<<1024, 256, 0, stream>>>(Z, nidx, g[2], exth, psumR(2), psqR(2));
    k_bnfin<256><<<256, 256, 0, stream>>>(exth, psumR(2), psqR(2), g[2], bb[2], invK, cath, 192);

    k_gemm<false, 128><<<dim3(64, 8), 256, 0, stream>>>(cath + 192, 960, W2h3, 256,
                                                        Z, 1024, nullptr, nullptr);
    k_gather<512><<<2048, 256, 0, stream>>>(Z, nidx, g[3], exth, psumR(3), psqR(3));
    k_bnfin<512><<<512, 256, 0, stream>>>(exth, psumR(3), psqR(3), g[3], bb[3], invK, cath, 448);

    // ---- feats = lrelu(bn(w4 @ cat)); finalize fused into feats_out's phase 0 ----
    k_gemm<true, 128><<<dim3(64, 8), 256, 0, stream>>>(cath, 960, w4h, 960, Y4, 1024,
                                                       psumR(4), psqR(4));
    k_feats_out<<<2048, 256, 0, stream>>>(Y4, psumR(4), psqR(4), g[4], bb[4], fo, pmax, psumn);
    k_pool2<<<512, 256, 0, stream>>>(pmax, psumn, z0);

    // ---- FC head (BN fused into FC blocks) ----
    k_fc<<<1024, 256, 0, stream>>>(z0, lw1, nullptr, g6, b6, 2048, 1024, z1);
    k_fc<<<512, 256, 0, stream>>>(z1, lw2, lb2, g7, b7, 1024, 512, z2);
    k_fc<<<256, 256, 0, stream>>>(z2, lw3, lb3, nullptr, nullptr, 512, 256, out);
}